// Round 12
// baseline (571.193 us; speedup 1.0000x reference)
//
#include <hip/hip_runtime.h>
#include <math.h>

// GAT pipeline. Layer2 collapsed (w_s = Σ α over src edges); z fp8 e4m3; MFMA
// GEMM1 with f32 score tile. Mega-kernel (gemm+scatter+frac), striped roles.
// R17: frac gather eliminated (cnt histogram). 526.3µs baseline.
// R18-R20: k_gat1 traffic shaping — DEAD END (random-gather LLC ceiling, ~117µs floor).
// R23: XCD-local atomics + rank-based atomic-free csr scatter. 515.3µs (-12;
//      mega dropped below 86µs).
// R24: 3-way gat1 diag split: aw2 = 86µs top non-gat1 kernel, WRITE_SIZE
//      UNCHANGED at 53MB -> wg-scope hint did NOT move fp atomics off the
//      memory-side RMW path (20 G atomics/s ceiling). Decision rule fired:
//      restructure aw2 atomic-free.
// R25: CSC PLAIN-STORE SCATTER for layer2 alpha-weights.
//      (a) prep hist also builds SRC histogram degS8/rkS (fused loop; rkS
//          aliases hneib+E, dead before gat1).
//      (b) scans fused for dst+src sides (scan1/scan3 grid 2B, scan2 both).
//      (c) mega scatter also writes csrPos[pD] = pS (edge's CSC slot).
//      (d) aw2: alphaCSC[csrPos[beg+j]] = a*inv — PLAIN 4B store, 0 atomics
//          (mega scatter proved plain stores >> RMW).
//      (e) new k_wsum: segmented sum alphaCSC -> wsrc; hsum reads wsrc.
//      Risk (pre-committed): if prep's +1.7M int atomics push prep >100µs,
//      next round moves the src-hist.

#define CAP 128

typedef unsigned int  uint_t;
typedef unsigned short ushort_t;
typedef __attribute__((ext_vector_type(8))) short short8;
typedef __attribute__((ext_vector_type(4))) float floatx4;
typedef __attribute__((ext_vector_type(2))) float floatx2;

__device__ __forceinline__ unsigned xcc_id(){
  unsigned x;
  asm volatile("s_getreg_b32 %0, hwreg(HW_REG_XCC_ID)" : "=s"(x));
  return x & 7u;
}
__device__ __forceinline__ float wred_sum(float v){
#pragma unroll
  for (int o = 1; o < 64; o <<= 1) v += __shfl_xor(v, o, 64);
  return v;
}
__device__ __forceinline__ float lrelu(float x){ return x >= 0.f ? x : 0.01f*x; }
__device__ __forceinline__ ushort_t f2b(float f){
  uint_t u = __float_as_uint(f);
  u = (u + 0x7FFFu + ((u >> 16) & 1u)) >> 16;   // RNE
  return (ushort_t)u;
}
__device__ __forceinline__ float b2f_lo(uint_t w){ return __uint_as_float(w << 16); }
__device__ __forceinline__ float b2f_hi(uint_t w){ return __uint_as_float(w & 0xFFFF0000u); }

// 8 fp8 values (uint2) x per-head alpha (float4) -> packed float2 accumulators
__device__ __forceinline__ void agg8(uint2 u, float4 al,
    floatx2& c00, floatx2& c01, floatx2& c10, floatx2& c11){
  floatx2 p0 = __builtin_amdgcn_cvt_pk_f32_fp8(u.x, false);
  floatx2 p1 = __builtin_amdgcn_cvt_pk_f32_fp8(u.x, true);
  floatx2 p2 = __builtin_amdgcn_cvt_pk_f32_fp8(u.y, false);
  floatx2 p3 = __builtin_amdgcn_cvt_pk_f32_fp8(u.y, true);
  floatx2 aXY = {al.x, al.y}, aZW = {al.z, al.w};
  c00 += aXY * p0;
  c01 += aZW * p1;
  c10 += aXY * p2;
  c11 += aZW * p3;
}

// ---------------- prep: W1 pack, score tile, v2, + hist (deg8+rk, degS8+rkS, cnt)
__global__ void k_prep(const float* __restrict__ W1, const float* __restrict__ W2,
                       const float* __restrict__ a1, const float* __restrict__ a2,
                       const int* __restrict__ dstI, const int* __restrict__ srcI, int E,
                       const int* __restrict__ fcm, int N3, int* __restrict__ cnt,
                       ushort_t* __restrict__ w1bp, float* __restrict__ v2,
                       int* __restrict__ deg8, int* __restrict__ rk,
                       int* __restrict__ degS8, int* __restrict__ rkS, int PAD){
  __shared__ float v[8][128];
  const int bx = blockIdx.x, t = threadIdx.x;
  if (bx < 128){
    int idx = bx*256 + t;
    int j = idx & 7, lane = (idx >> 3) & 63, ks = (idx >> 9) & 3, tt = idx >> 11;
    int n = tt*16 + (lane & 15), k = ks*32 + (lane >> 4)*8 + j;
    int hh = tt >> 2, m = tt & 3;
    int pt = (m < 2) ? (hh*2 + m) : (8 + hh*2 + (m - 2));
    w1bp[((pt*4 + ks)*64 + lane)*8 + j] = f2b(W1[n*128 + k]);
  } else if (bx == 128){
    for (int o = t; o < 1024; o += 256){
      int col = o >> 7, k = o & 127, hh = col & 3, off = (col >> 2)*64;
      float s = 0.f;
      for (int n = 0; n < 64; n++) s += a1[hh*128 + off + n] * W1[(hh*64 + n)*128 + k];
      v[col][k] = s;
    }
    __syncthreads();
    for (int idx = t; idx < 2048; idx += 256){
      int j = idx & 7, lane = (idx >> 3) & 63, ks = idx >> 9;
      int col = lane & 15, k = ks*32 + (lane >> 4)*8 + j;
      w1bp[32768 + idx] = (col < 8) ? f2b(v[col][k]) : (ushort_t)0;   // packed tile 16
    }
  } else if (bx == 129){
    float s0 = 0.f, s1 = 0.f;
    for (int j = 0; j < 64; j++){
      float wjk = W2[j*256 + t];
      s0 += wjk * a2[j];
      s1 += wjk * a2[64 + j];
    }
    v2[t] = s0; v2[256 + t] = s1;
  } else {
    const int nb = gridDim.x - 130;
    const unsigned xcd = xcc_id();
    int* myDeg  = deg8  + (size_t)xcd * PAD;
    int* myDegS = degS8 + (size_t)xcd * PAD;
    for (int i = (bx-130)*256 + t; i < E; i += nb*256){
      int d = dstI[i];
      int s = srcI[i];
      int r  = __hip_atomic_fetch_add(&myDeg[d], 1, __ATOMIC_RELAXED,
                                      __HIP_MEMORY_SCOPE_WORKGROUP);
      int rs = __hip_atomic_fetch_add(&myDegS[s], 1, __ATOMIC_RELAXED,
                                      __HIP_MEMORY_SCOPE_WORKGROUP);
      rk[i]  = (int)((xcd << 28) | (unsigned)r);
      rkS[i] = (int)((xcd << 28) | (unsigned)rs);
    }
    for (int i = (bx-130)*256 + t; i < N3; i += nb*256){
      int v3 = fcm[i];
      atomicAdd(&cnt[v3*3 + (i % 3)], 1);     // 300k only — keep device scope
    }
  }
}

// ---------------- scans (fused dst+src: blockIdx < B -> dst side, else src side)
__global__ __launch_bounds__(256) void k_scan1(const int* __restrict__ deg8,
    const int* __restrict__ degS8, int* __restrict__ partD,
    int* __restrict__ partS, int B, int PAD){
  __shared__ int tmp[256];
  const int bx = blockIdx.x;
  const bool srcSide = bx >= B;
  const int* dp = srcSide ? degS8 : deg8;
  int* pp = srcSide ? partS : partD;
  const int row = srcSide ? (bx - B) : bx;
  int t = threadIdx.x, i = row*256 + t;
  int v = 0;
#pragma unroll
  for (int x = 0; x < 8; x++) v += dp[(size_t)x*PAD + i];
  tmp[t] = v;
  __syncthreads();
  for (int off = 128; off > 0; off >>= 1){
    if (t < off) tmp[t] += tmp[t+off];
    __syncthreads();
  }
  if (t == 0) pp[row] = tmp[0];
}
__global__ __launch_bounds__(512) void k_scan2(int* __restrict__ partD,
    int* __restrict__ partS, int B){
  __shared__ int tmp[512];
  int t = threadIdx.x;
  // dst side
  int v = (t < B) ? partD[t] : 0;
  tmp[t] = v; __syncthreads();
  for (int off = 1; off < 512; off <<= 1){
    int x = (t >= off) ? tmp[t-off] : 0;
    __syncthreads();
    tmp[t] += x;
    __syncthreads();
  }
  if (t < B) partD[t] = tmp[t] - v;
  __syncthreads();
  // src side
  int v2 = (t < B) ? partS[t] : 0;
  tmp[t] = v2; __syncthreads();
  for (int off = 1; off < 512; off <<= 1){
    int x = (t >= off) ? tmp[t-off] : 0;
    __syncthreads();
    tmp[t] += x;
    __syncthreads();
  }
  if (t < B) partS[t] = tmp[t] - v2;
}
// scan3: rowptr = excl scan of Σx deg; base8[x][i] = per-XCD sub-range start
__global__ __launch_bounds__(256) void k_scan3(const int* __restrict__ deg8,
    const int* __restrict__ degS8,
    const int* __restrict__ partD, const int* __restrict__ partS,
    int* __restrict__ rowptr, int* __restrict__ rowptrS,
    int* __restrict__ base8, int* __restrict__ baseS8, int B, int PAD){
  __shared__ int tmp[256];
  const int bx = blockIdx.x;
  const bool srcSide = bx >= B;
  const int* dp = srcSide ? degS8 : deg8;
  const int* pp = srcSide ? partS : partD;
  int* rp = srcSide ? rowptrS : rowptr;
  int* bp = srcSide ? baseS8 : base8;
  const int row = srcSide ? (bx - B) : bx;
  int t = threadIdx.x, i = row*256 + t;
  int d8[8]; int v = 0;
#pragma unroll
  for (int x = 0; x < 8; x++){ d8[x] = dp[(size_t)x*PAD + i]; v += d8[x]; }
  tmp[t] = v; __syncthreads();
  for (int off = 1; off < 256; off <<= 1){
    int x = (t >= off) ? tmp[t-off] : 0;
    __syncthreads();
    tmp[t] += x;
    __syncthreads();
  }
  int excl = tmp[t] - v + pp[row];
  rp[i] = excl;
  int run = excl;
#pragma unroll
  for (int x = 0; x < 8; x++){ bp[(size_t)x*PAD + i] = run; run += d8[x]; }
}

// ---------------- MEGA (striped roles): gemm + scatter(atomic-free, csr+csrPos) + frac
__global__ __launch_bounds__(512, 4) void k_mega(const float* __restrict__ h,
    const ushort_t* __restrict__ w1bp,
    uint_t* __restrict__ z8, float* __restrict__ s1s, float* __restrict__ s1d, int N,
    const int* __restrict__ srcI, const int* __restrict__ dstI,
    const int* __restrict__ rk, const int* __restrict__ rkS,
    const int* __restrict__ base8, const int* __restrict__ baseS8, int PAD,
    int* __restrict__ csr, int* __restrict__ csrPos, int E,
    int Gg, int Gs, int G, int step,
    const int* __restrict__ cnt, float* __restrict__ accFrac)
{
  static __shared__ __align__(16) char smem[36864];
  const int tid = threadIdx.x;
  const int id = (int)(((unsigned long long)blockIdx.x * (unsigned)step) % (unsigned)G);
  if (id < Gg){
    ushort_t* ldsB = (ushort_t*)smem;
    const int wave = tid >> 6, lane = tid & 63;
    const int quad = lane >> 4, l16 = lane & 15;
    const int row0 = id*128 + wave*16;
    const bool act = row0 < N;
    const int ar = act ? ((row0 + l16 < N) ? (row0 + l16) : (N - 1)) : 0;
    short8 AHI[4], ALO[4];
    if (act){
#pragma unroll
      for (int ks = 0; ks < 4; ks++){
        const float* ap = &h[(size_t)ar*128 + ks*32 + quad*8];
        float4 v0 = *(const float4*)ap;
        float4 v1 = *(const float4*)(ap + 4);
        float vv[8] = {v0.x,v0.y,v0.z,v0.w,v1.x,v1.y,v1.z,v1.w};
#pragma unroll
        for (int j = 0; j < 8; j++){
          ushort_t hb = f2b(vv[j]);
          float hf = __uint_as_float((uint_t)hb << 16);
          AHI[ks][j] = (short)hb;
          ALO[ks][j] = (short)f2b(vv[j] - hf);
        }
      }
    }
#pragma unroll
    for (int half = 0; half < 2; half++){
      __syncthreads();
      {
        const int cnt4 = half ? 2304 : 2048;                 // uint4 count
        const uint4* src = (const uint4*)w1bp + (half ? 2048 : 0);
        uint4* dst = (uint4*)ldsB;
        for (int i = tid; i < cnt4; i += 512) dst[i] = src[i];
      }
      __syncthreads();
      if (!act) continue;
      const int nt = half ? 9 : 8;
      floatx4 c[9];
#pragma unroll
      for (int i = 0; i < 9; i++) c[i] = (floatx4){0.f,0.f,0.f,0.f};
#pragma unroll
      for (int ks = 0; ks < 4; ks++){
        for (int i = 0; i < nt; i++){
          short8 b = *(const short8*)&ldsB[(size_t)((i*4 + ks)*64 + lane)*8];
          c[i] = __builtin_amdgcn_mfma_f32_16x16x32_bf16(AHI[ks], b, c[i], 0, 0, 0);
        }
        if (half){
          short8 b = *(const short8*)&ldsB[(size_t)((8*4 + ks)*64 + lane)*8];
          c[8] = __builtin_amdgcn_mfma_f32_16x16x32_bf16(ALO[ks], b, c[8], 0, 0, 0);
        }
      }
      const int m0 = half ? 2 : 0;
#pragma unroll
      for (int i = 0; i < 4; i++){
        const int r = row0 + quad*4 + i;
        if (r >= N) continue;
#pragma unroll
        for (int dm = 0; dm < 2; dm++){
          int u = 0;
          u = __builtin_amdgcn_cvt_pk_fp8_f32(c[0*2+dm][i], c[1*2+dm][i], u, false);
          u = __builtin_amdgcn_cvt_pk_fp8_f32(c[2*2+dm][i], c[3*2+dm][i], u, true);
          z8[(size_t)r*64 + (m0+dm)*16 + l16] = (uint_t)u;
        }
        if (half){
          const float sv = c[8][i];
          if (l16 < 4) s1s[r*4 + l16] = sv;
          else if (l16 < 8) s1d[r*4 + (l16 - 4)] = sv;
        }
      }
    }
  } else if (id < Gg + Gs){
    // ---- scatter role: rank-based, NO atomics; csr + CSC slot
    const int i = (id - Gg)*512 + tid;
    if (i < E){
      const int d = dstI[i];
      const int s = srcI[i];
      const uint_t uD = (uint_t)rk[i];
      const uint_t uS = (uint_t)rkS[i];
      const int pD = base8 [(size_t)(uD >> 28)*PAD + d] + (int)(uD & 0x0FFFFFFFu);
      const int pS = baseS8[(size_t)(uS >> 28)*PAD + s] + (int)(uS & 0x0FFFFFFFu);
      csr[pD]    = s;
      csrPos[pD] = pS;
    }
  } else {
    // frac role: streaming cnt-weighted sum over contiguous h rows.
    float (*red)[384] = (float(*)[384])smem;
    const int wave = tid >> 6, lane = tid & 63;
    const int g = lane >> 5, li = lane & 31;
    const int Gf = G - Gg - Gs;
    const int stream0 = (id - Gg - Gs)*16 + wave*2 + g;
    const int step16 = Gf * 16;
    float4 a0 = {0,0,0,0}, a1 = {0,0,0,0}, a2 = {0,0,0,0};
    for (int n = stream0; n < N; n += step16){
      const float w0 = (float)cnt[n*3];
      const float w1 = (float)cnt[n*3+1];
      const float w2 = (float)cnt[n*3+2];
      float4 v = *(const float4*)&h[(size_t)n*128 + li*4];
      a0.x += w0*v.x; a0.y += w0*v.y; a0.z += w0*v.z; a0.w += w0*v.w;
      a1.x += w1*v.x; a1.y += w1*v.y; a1.z += w1*v.z; a1.w += w1*v.w;
      a2.x += w2*v.x; a2.y += w2*v.y; a2.z += w2*v.z; a2.w += w2*v.w;
    }
    const int w16 = wave*2 + g;
    *(float4*)&red[w16][0*128 + li*4] = a0;
    *(float4*)&red[w16][1*128 + li*4] = a1;
    *(float4*)&red[w16][2*128 + li*4] = a2;
    __syncthreads();
    for (int i = tid; i < 384; i += 512){
      float v = 0.f;
#pragma unroll
      for (int w = 0; w < 16; w++) v += red[w][i];
      atomicAdd(&accFrac[i], v);
    }
  }
}

// ---------------- layer1 GAT aggregation + ELU -> hneib bf16 + fused layer2 scores
// dbase param — launched 2x over disjoint dst halves (keeps table unmasked).
__global__ __launch_bounds__(256) void k_gat1(
    const uint_t* __restrict__ z8, const float* __restrict__ s1src, const float* __restrict__ s1dst,
    const int* __restrict__ rowptr, const int* __restrict__ csr, const float* __restrict__ v2,
    uint_t* __restrict__ hneib, float* __restrict__ s2s, float* __restrict__ s2d, int N, int dbase)
{
  __shared__ int   sbuf[4][CAP];                 // s*64 (dword offset into z8)
  __shared__ __align__(16) float4 ebuf[4][CAP];
  __shared__ float v2s[512];
  const int tid = threadIdx.x;
  v2s[tid] = v2[tid];
  v2s[tid + 256] = v2[tid + 256];
  __syncthreads();
  const int wave = tid >> 6, lane = tid & 63;
  const int dst = (dbase + blockIdx.x)*4 + wave;
  if (dst >= N) return;
  const int beg = rowptr[dst];
  const int deg = rowptr[dst+1] - beg;
  const float4 sd = *(const float4*)&s1dst[dst*4];
  float t0=0.f,t1=0.f,t2=0.f,t3=0.f;
  for (int j = lane; j < deg; j += 64){
    int s = csr[beg+j];
    float4 sv = *(const float4*)&s1src[s*4];
    float4 a;
    a.x = __expf(lrelu(sv.x+sd.x)); a.y = __expf(lrelu(sv.y+sd.y));
    a.z = __expf(lrelu(sv.z+sd.z)); a.w = __expf(lrelu(sv.w+sd.w));
    if (j < CAP){ sbuf[wave][j] = s*64; ebuf[wave][j] = a; }
    t0 += a.x; t1 += a.y; t2 += a.z; t3 += a.w;
  }
  const float inv[4] = {1.f/wred_sum(t0), 1.f/wred_sum(t1), 1.f/wred_sum(t2), 1.f/wred_sum(t3)};
  const int eh = lane >> 5, li = lane & 31;
  floatx2 c00 = {0.f,0.f}, c01 = {0.f,0.f}, c10 = {0.f,0.f}, c11 = {0.f,0.f};
  if (deg <= CAP){
    const int j0 = (eh < deg) ? eh : 0;
    int offc = sbuf[wave][j0];
    float4 alc = ebuf[wave][j0];
    uint2 uc = *((const uint2*)(z8 + offc) + li);
    for (int jj = 0; jj + 2 <= deg; jj += 2){
      const int jn = jj + 2 + eh;
      const int jnc = (jn < deg) ? jn : (jj + eh);
      const int offn = sbuf[wave][jnc];
      const float4 aln = ebuf[wave][jnc];
      const uint2 un = *((const uint2*)(z8 + offn) + li);   // issue before use of uc
      agg8(uc, alc, c00, c01, c10, c11);
      uc = un; alc = aln;
    }
    if ((deg & 1) && eh == 0)
      agg8(uc, alc, c00, c01, c10, c11);
  } else {
    for (int jj = 0; jj < deg; jj += 2){
      const int j = jj + eh;
      const bool v = j < deg;
      const int jc = v ? j : jj;
      int off; float4 al;
      if (jc < CAP){ off = sbuf[wave][jc]; al = ebuf[wave][jc]; }
      else {
        int s = csr[beg+jc];
        off = s*64;
        float4 sv = *(const float4*)&s1src[s*4];
        al.x = __expf(lrelu(sv.x+sd.x)); al.y = __expf(lrelu(sv.y+sd.y));
        al.z = __expf(lrelu(sv.z+sd.z)); al.w = __expf(lrelu(sv.w+sd.w));
      }
      if (!v){ al.x=0.f; al.y=0.f; al.z=0.f; al.w=0.f; }
      uint2 u = *((const uint2*)(z8 + off) + li);
      agg8(u, al, c00, c01, c10, c11);
    }
  }
  float acc[2][4] = {{c00.x, c00.y, c01.x, c01.y},
                     {c10.x, c10.y, c11.x, c11.y}};
#pragma unroll
  for (int k = 0; k < 2; k++)
#pragma unroll
    for (int hh = 0; hh < 4; hh++) acc[k][hh] += __shfl_xor(acc[k][hh], 32, 64);
  const float* vv = &v2s[eh*256];
  float p = 0.f;
#pragma unroll
  for (int hh = 0; hh < 4; hh++){
    float e0 = acc[0][hh]*inv[hh]; e0 = e0 > 0.f ? e0 : expm1f(e0);
    float e1 = acc[1][hh]*inv[hh]; e1 = e1 > 0.f ? e1 : expm1f(e1);
    p += e0 * vv[hh*64 + 2*li] + e1 * vv[hh*64 + 2*li + 1];
    if ((hh >> 1) == eh)
      hneib[(size_t)dst*128 + hh*32 + li] = (uint_t)f2b(e0) | ((uint_t)f2b(e1) << 16);
  }
#pragma unroll
  for (int o = 1; o < 32; o <<= 1) p += __shfl_xor(p, o, 64);
  if (lane == 0)  s2s[dst] = p;
  if (lane == 32) s2d[dst] = p;
}

// ---------------- layer2 alpha-weights: atomic-FREE plain-store CSC scatter
__global__ __launch_bounds__(256) void k_aw2(
    const float* __restrict__ s2s, const float* __restrict__ s2d,
    const int* __restrict__ rowptr, const int* __restrict__ csr,
    const int* __restrict__ csrPos, float* __restrict__ alphaCSC, int N)
{
  __shared__ int   sbuf[4][CAP];
  __shared__ float ebuf[4][CAP];
  const int wave = threadIdx.x >> 6, lane = threadIdx.x & 63;
  const int dst = blockIdx.x*4 + wave;
  if (dst >= N) return;
  const int beg = rowptr[dst], deg = rowptr[dst+1] - beg;
  const float sd = s2d[dst];
  float ts = 0.f;
  for (int j = lane; j < deg; j += 64){
    int s = csr[beg+j];
    float a = __expf(lrelu(s2s[s] + sd));
    if (j < CAP){ sbuf[wave][j] = s; ebuf[wave][j] = a; }
    ts += a;
  }
  const float inv = 1.f/wred_sum(ts);
  for (int j = lane; j < deg; j += 64){
    float a;
    if (j < CAP){ a = ebuf[wave][j]; }
    else { int s = csr[beg+j]; a = __expf(lrelu(s2s[s] + sd)); }
    alphaCSC[csrPos[beg+j]] = a * inv;      // plain random 4B store
  }
}

// ---------------- per-src segmented sum: wsrc[n] = Σ alphaCSC[rowptrS[n]..)
__global__ __launch_bounds__(256) void k_wsum(const float* __restrict__ alphaCSC,
    const int* __restrict__ rowptrS, float* __restrict__ wsrc, int N)
{
  const int n = blockIdx.x*256 + threadIdx.x;
  if (n >= N) return;
  const int b = rowptrS[n], e = rowptrS[n+1];
  float s = 0.f;
  for (int k = b; k < e; k++) s += alphaCSC[k];
  wsrc[n] = s;
}

// ---------------- weighted hnei sum (coalesced)
__global__ __launch_bounds__(256) void k_hsum(const uint_t* __restrict__ hneib,
    const float* __restrict__ wsrc, float* __restrict__ acc256, int N)
{
  __shared__ float pr[512];
  const int t = threadIdx.x;
  const int h2 = t >> 7, p = t & 127;
  float a0 = 0.f, a1 = 0.f;
  const int step = gridDim.x * 2;
  for (int n = blockIdx.x*2 + h2; n < N; n += step){
    float wn = wsrc[n];
    uint_t u = hneib[(size_t)n*128 + p];
    a0 += wn * b2f_lo(u);
    a1 += wn * b2f_hi(u);
  }
  pr[h2*256 + 2*p]     = a0;
  pr[h2*256 + 2*p + 1] = a1;
  __syncthreads();
  float v = pr[t] + pr[256 + t];
  int pp = t >> 1;
  int d = (pp >> 5)*64 + 2*(pp & 31) + (t & 1);
  atomicAdd(&acc256[d], v);
}

// ---------------- finalize
__global__ __launch_bounds__(256) void k_finalize(const float* __restrict__ acc256,
    const float* __restrict__ accFrac, const float* __restrict__ W2,
    const float* __restrict__ frw, const float* __restrict__ frf,
    const float* __restrict__ fc2, float* __restrict__ out, float invN)
{
  __shared__ float mh[256], nei[64], g[384], mm[192], hfrac[64];
  int t = threadIdx.x;
  mh[t] = acc256[t] * invN;
  for (int i = t; i < 384; i += 256) g[i] = accFrac[i] * invN;
  __syncthreads();
  if (t < 64){
    float s = 0.f;
    for (int k = 0; k < 256; k++) s += W2[t*256 + k] * mh[k];
    nei[t] = s;
  }
  for (int i = t; i < 192; i += 256){
    int s = i >> 6, d = i & 63;
    const float* w = frw + (size_t)(s*64 + d)*128;
    const float* gs = g + s*128;
    float sum = 0.f;
    for (int k = 0; k < 128; k++) sum += gs[k]*w[k];
    mm[i] = sum;
  }
  __syncthreads();
  if (t < 64){
    float s = 0.f;
    for (int k = 0; k < 192; k++) s += mm[k]*frf[t*192 + k];
    hfrac[t] = s;
  }
  __syncthreads();
  if (t < 64){
    float o = 0.f;
    for (int k = 0; k < 64; k++)
      o += fc2[t*128 + k]*nei[k] + fc2[t*128 + 64 + k]*hfrac[k];
    out[t] = o;
  }
}

extern "C" void kernel_launch(void* const* d_in, const int* in_sizes, int n_in,
                              void* d_out, int out_size, void* d_ws, size_t ws_size,
                              hipStream_t stream)
{
  const float* h    = (const float*)d_in[0];
  const int*   srcI = (const int*)  d_in[1];
  const int*   dstI = (const int*)  d_in[2];
  const int*   fcm  = (const int*)  d_in[3];
  const float* l1fc = (const float*)d_in[4];
  const float* l1at = (const float*)d_in[5];
  const float* l2fc = (const float*)d_in[6];
  const float* l2at = (const float*)d_in[7];
  const float* frw  = (const float*)d_in[8];
  const float* frf  = (const float*)d_in[9];
  const float* fc2  = (const float*)d_in[10];
  float* out = (float*)d_out;
  (void)n_in; (void)out_size; (void)ws_size;

  const int N = in_sizes[0] / 128;
  const int E = in_sizes[1];
  const int B = (N + 256) / 256;     // ceil((N+1)/256) so rowptr[N] is covered
  const int PAD = B * 256;

  char* w = (char*)d_ws;
  size_t off = 0;
  auto alloc = [&](size_t bytes) -> char* {
    char* p = w + off; off = (off + bytes + 255) & ~(size_t)255; return p;
  };
  uint_t* z8    = (uint_t*)alloc((size_t)N*64*4);    // 25.6 MB fp8 z
  uint_t* hneib = (uint_t*)alloc((size_t)N*128*4);   // 51.2 MB packed bf16 hnei
  int*    rk    = (int*)hneib;                       // rank arrays alias hneib
  int*    rkS   = rk + E;                            // (dead before gat1 writes hneib)
  float* s1s  = (float*)alloc((size_t)N*4*4);
  float* s1d  = (float*)alloc((size_t)N*4*4);
  float* s2s  = (float*)alloc((size_t)N*4);
  float* s2d  = (float*)alloc((size_t)N*4);
  // ---- zeroed region (one memset): deg8, degS8, cnt, acc256, accFrac
  int*   deg8    = (int*)  alloc((size_t)8*PAD*4);   // XCD-local dst histograms
  int*   degS8   = (int*)  alloc((size_t)8*PAD*4);   // XCD-local src histograms
  int*   cnt     = (int*)  alloc((size_t)N*3*4);     // fcm occurrence histogram
  float* acc256  = (float*)alloc(256*4);
  float* accFrac = (float*)alloc(384*4);
  const size_t zbytes = (size_t)((char*)accFrac + 384*4 - (char*)deg8);
  // ---- rest
  int*   rowptr  = (int*)alloc((size_t)PAD*4);
  int*   rowptrS = (int*)alloc((size_t)PAD*4);
  int*   base8   = (int*)alloc((size_t)8*PAD*4);
  int*   baseS8  = (int*)alloc((size_t)8*PAD*4);
  int*   partD   = (int*)alloc(512*4);
  int*   partS   = (int*)alloc(512*4);
  int*   csr     = (int*)alloc((size_t)E*4);
  int*   csrPos  = (int*)alloc((size_t)E*4);
  float* alphaCSC= (float*)alloc((size_t)E*4);       // written 1x per slot, no init
  float* wsrc    = (float*)alloc((size_t)N*4);
  ushort_t* w1bp = (ushort_t*)alloc(34816*2);   // 16 z-tiles (permuted) + score tile
  float* v2     = (float*)alloc(512*4);

  hipMemsetAsync(deg8, 0, zbytes, stream);

  hipLaunchKernelGGL(k_prep,  dim3(130 + 512), dim3(256), 0, stream,
                     l1fc, l2fc, l1at, l2at, dstI, srcI, E, fcm, 3*N, cnt, w1bp, v2,
                     deg8, rk, degS8, rkS, PAD);
  hipLaunchKernelGGL(k_scan1, dim3(2*B), dim3(256), 0, stream,
                     deg8, degS8, partD, partS, B, PAD);
  hipLaunchKernelGGL(k_scan2, dim3(1),   dim3(512), 0, stream, partD, partS, B);
  hipLaunchKernelGGL(k_scan3, dim3(2*B), dim3(256), 0, stream,
                     deg8, degS8, partD, partS, rowptr, rowptrS, base8, baseS8, B, PAD);

  const int Gg = (N + 127) / 128;
  const int Gs = (E + 511) / 512;
  const int Gf = 512;
  const int G  = Gg + Gs + Gf;
  int step = (int)(G * 0.618) | 1;
  auto gcd = [](int a, int b){ while (b){ int t = a % b; a = b; b = t; } return a; };
  while (gcd(step, G) != 1) step += 2;

  hipLaunchKernelGGL(k_mega,  dim3(G), dim3(512), 0, stream,
                     h, w1bp, z8, s1s, s1d, N,
                     srcI, dstI, rk, rkS, base8, baseS8, PAD, csr, csrPos, E,
                     Gg, Gs, G, step, cnt, accFrac);
  const int nb  = (N + 3) / 4;
  const int nb1 = nb / 2;
  hipLaunchKernelGGL(k_gat1,  dim3(nb1),      dim3(256), 0, stream,
                     z8, s1s, s1d, rowptr, csr, v2, hneib, s2s, s2d, N, 0);
  hipLaunchKernelGGL(k_gat1,  dim3(nb - nb1), dim3(256), 0, stream,
                     z8, s1s, s1d, rowptr, csr, v2, hneib, s2s, s2d, N, nb1);
  hipLaunchKernelGGL(k_aw2,   dim3(nb),       dim3(256), 0, stream,
                     s2s, s2d, rowptr, csr, csrPos, alphaCSC, N);
  hipLaunchKernelGGL(k_wsum,  dim3((N+255)/256), dim3(256), 0, stream,
                     alphaCSC, rowptrS, wsrc, N);
  hipLaunchKernelGGL(k_hsum,  dim3(608),      dim3(256), 0, stream,
                     hneib, wsrc, acc256, N);
  hipLaunchKernelGGL(k_finalize, dim3(1),     dim3(256), 0, stream,
                     acc256, accFrac, l2fc, frw, frf, fc2, out, 1.0f/(float)N);
}

// Round 13
// 562.277 us; speedup vs baseline: 1.0159x; 1.0159x over previous
//
#include <hip/hip_runtime.h>
#include <math.h>

// GAT pipeline. Layer2 collapsed; z fp8 e4m3; MFMA GEMM1. Mega-kernel with
// striped roles (gemm + scatter + srcHist + frac).
// R17 baseline 526.3. R23 XCD-hist + rank scatter: 515.3 (best).
// R24: aw2=86µs, WRITE 53MB -> fp atomics at LLC ~20G/s, scope hint dead.
// R25: CSC plain-store aw2 (correct, proven) but 2nd histogram serialized in
//      prep -> prep 150µs, total 571. REGRESSION. Lesson: ALL global atomics
//      ~20-25G/s memory-side regardless of scope; don't serialize two
//      histogram passes.
// R26: OVERLAP the src histogram with mega's compute. srcHist becomes a 4th
//      striped role in k_mega (atomic RMW unit is disjoint from VALU/MFMA/
//      HBM-read -> m114-style overlap). Mega's scatter writes csrEid instead
//      of csrPos (rkS is concurrent -> race-free); aw2 derives pS itself via
//      rkS[eid]/baseS8 gathers (plain loads, 2.5TB/s path). Src-side scans
//      run between mega and gat1. rkS = own buffer (lives until aw2).
//      Pre-commit: mega >130µs => overlap premise wrong, revert src-side.

#define CAP 128

typedef unsigned int  uint_t;
typedef unsigned short ushort_t;
typedef __attribute__((ext_vector_type(8))) short short8;
typedef __attribute__((ext_vector_type(4))) float floatx4;
typedef __attribute__((ext_vector_type(2))) float floatx2;

__device__ __forceinline__ unsigned xcc_id(){
  unsigned x;
  asm volatile("s_getreg_b32 %0, hwreg(HW_REG_XCC_ID)" : "=s"(x));
  return x & 7u;
}
__device__ __forceinline__ float wred_sum(float v){
#pragma unroll
  for (int o = 1; o < 64; o <<= 1) v += __shfl_xor(v, o, 64);
  return v;
}
__device__ __forceinline__ float lrelu(float x){ return x >= 0.f ? x : 0.01f*x; }
__device__ __forceinline__ ushort_t f2b(float f){
  uint_t u = __float_as_uint(f);
  u = (u + 0x7FFFu + ((u >> 16) & 1u)) >> 16;   // RNE
  return (ushort_t)u;
}
__device__ __forceinline__ float b2f_lo(uint_t w){ return __uint_as_float(w << 16); }
__device__ __forceinline__ float b2f_hi(uint_t w){ return __uint_as_float(w & 0xFFFF0000u); }

// 8 fp8 values (uint2) x per-head alpha (float4) -> packed float2 accumulators
__device__ __forceinline__ void agg8(uint2 u, float4 al,
    floatx2& c00, floatx2& c01, floatx2& c10, floatx2& c11){
  floatx2 p0 = __builtin_amdgcn_cvt_pk_f32_fp8(u.x, false);
  floatx2 p1 = __builtin_amdgcn_cvt_pk_f32_fp8(u.x, true);
  floatx2 p2 = __builtin_amdgcn_cvt_pk_f32_fp8(u.y, false);
  floatx2 p3 = __builtin_amdgcn_cvt_pk_f32_fp8(u.y, true);
  floatx2 aXY = {al.x, al.y}, aZW = {al.z, al.w};
  c00 += aXY * p0;
  c01 += aZW * p1;
  c10 += aXY * p2;
  c11 += aZW * p3;
}

// ---------------- prep: W1 pack, score tile, v2, + hist (deg8+rk, cnt) [R23 form]
__global__ void k_prep(const float* __restrict__ W1, const float* __restrict__ W2,
                       const float* __restrict__ a1, const float* __restrict__ a2,
                       const int* __restrict__ dstI, int E,
                       const int* __restrict__ fcm, int N3, int* __restrict__ cnt,
                       ushort_t* __restrict__ w1bp, float* __restrict__ v2,
                       int* __restrict__ deg8, int* __restrict__ rk, int PAD){
  __shared__ float v[8][128];
  const int bx = blockIdx.x, t = threadIdx.x;
  if (bx < 128){
    int idx = bx*256 + t;
    int j = idx & 7, lane = (idx >> 3) & 63, ks = (idx >> 9) & 3, tt = idx >> 11;
    int n = tt*16 + (lane & 15), k = ks*32 + (lane >> 4)*8 + j;
    int hh = tt >> 2, m = tt & 3;
    int pt = (m < 2) ? (hh*2 + m) : (8 + hh*2 + (m - 2));
    w1bp[((pt*4 + ks)*64 + lane)*8 + j] = f2b(W1[n*128 + k]);
  } else if (bx == 128){
    for (int o = t; o < 1024; o += 256){
      int col = o >> 7, k = o & 127, hh = col & 3, off = (col >> 2)*64;
      float s = 0.f;
      for (int n = 0; n < 64; n++) s += a1[hh*128 + off + n] * W1[(hh*64 + n)*128 + k];
      v[col][k] = s;
    }
    __syncthreads();
    for (int idx = t; idx < 2048; idx += 256){
      int j = idx & 7, lane = (idx >> 3) & 63, ks = idx >> 9;
      int col = lane & 15, k = ks*32 + (lane >> 4)*8 + j;
      w1bp[32768 + idx] = (col < 8) ? f2b(v[col][k]) : (ushort_t)0;   // packed tile 16
    }
  } else if (bx == 129){
    float s0 = 0.f, s1 = 0.f;
    for (int j = 0; j < 64; j++){
      float wjk = W2[j*256 + t];
      s0 += wjk * a2[j];
      s1 += wjk * a2[64 + j];
    }
    v2[t] = s0; v2[256 + t] = s1;
  } else {
    const int nb = gridDim.x - 130;
    const unsigned xcd = xcc_id();
    int* myDeg = deg8 + (size_t)xcd * PAD;
    for (int i = (bx-130)*256 + t; i < E; i += nb*256){
      int d = dstI[i];
      int r = __hip_atomic_fetch_add(&myDeg[d], 1, __ATOMIC_RELAXED,
                                     __HIP_MEMORY_SCOPE_WORKGROUP);
      rk[i] = (int)((xcd << 28) | (unsigned)r);
    }
    for (int i = (bx-130)*256 + t; i < N3; i += nb*256){
      int v3 = fcm[i];
      atomicAdd(&cnt[v3*3 + (i % 3)], 1);     // 300k only
    }
  }
}

// ---------------- scans (side-parameterized, launched once per side)
__global__ __launch_bounds__(256) void k_scan1(const int* __restrict__ dp,
    int* __restrict__ part, int PAD){
  __shared__ int tmp[256];
  int t = threadIdx.x, i = blockIdx.x*256 + t;
  int v = 0;
#pragma unroll
  for (int x = 0; x < 8; x++) v += dp[(size_t)x*PAD + i];
  tmp[t] = v;
  __syncthreads();
  for (int off = 128; off > 0; off >>= 1){
    if (t < off) tmp[t] += tmp[t+off];
    __syncthreads();
  }
  if (t == 0) part[blockIdx.x] = tmp[0];
}
__global__ __launch_bounds__(512) void k_scan2(int* __restrict__ part, int B){
  __shared__ int tmp[512];
  int t = threadIdx.x;
  int v = (t < B) ? part[t] : 0;
  tmp[t] = v; __syncthreads();
  for (int off = 1; off < 512; off <<= 1){
    int x = (t >= off) ? tmp[t-off] : 0;
    __syncthreads();
    tmp[t] += x;
    __syncthreads();
  }
  if (t < B) part[t] = tmp[t] - v;   // exclusive
}
__global__ __launch_bounds__(256) void k_scan3(const int* __restrict__ dp,
    const int* __restrict__ part, int* __restrict__ rowp,
    int* __restrict__ basep, int PAD){
  __shared__ int tmp[256];
  int t = threadIdx.x, i = blockIdx.x*256 + t;
  int d8[8]; int v = 0;
#pragma unroll
  for (int x = 0; x < 8; x++){ d8[x] = dp[(size_t)x*PAD + i]; v += d8[x]; }
  tmp[t] = v; __syncthreads();
  for (int off = 1; off < 256; off <<= 1){
    int x = (t >= off) ? tmp[t-off] : 0;
    __syncthreads();
    tmp[t] += x;
    __syncthreads();
  }
  int excl = tmp[t] - v + part[blockIdx.x];
  rowp[i] = excl;
  int run = excl;
#pragma unroll
  for (int x = 0; x < 8; x++){ basep[(size_t)x*PAD + i] = run; run += d8[x]; }
}

// ---------------- MEGA (striped): gemm + scatter(csr+csrEid) + srcHist + frac
__global__ __launch_bounds__(512, 4) void k_mega(const float* __restrict__ h,
    const ushort_t* __restrict__ w1bp,
    uint_t* __restrict__ z8, float* __restrict__ s1s, float* __restrict__ s1d, int N,
    const int* __restrict__ srcI, const int* __restrict__ dstI,
    const int* __restrict__ rk, const int* __restrict__ base8, int PAD,
    int* __restrict__ csr, int* __restrict__ csrEid,
    int* __restrict__ degS8, int* __restrict__ rkS, int E,
    int Gg, int Gs, int Gh, int G, int step,
    const int* __restrict__ cnt, float* __restrict__ accFrac)
{
  static __shared__ __align__(16) char smem[36864];
  const int tid = threadIdx.x;
  const int id = (int)(((unsigned long long)blockIdx.x * (unsigned)step) % (unsigned)G);
  if (id < Gg){
    ushort_t* ldsB = (ushort_t*)smem;
    const int wave = tid >> 6, lane = tid & 63;
    const int quad = lane >> 4, l16 = lane & 15;
    const int row0 = id*128 + wave*16;
    const bool act = row0 < N;
    const int ar = act ? ((row0 + l16 < N) ? (row0 + l16) : (N - 1)) : 0;
    short8 AHI[4], ALO[4];
    if (act){
#pragma unroll
      for (int ks = 0; ks < 4; ks++){
        const float* ap = &h[(size_t)ar*128 + ks*32 + quad*8];
        float4 v0 = *(const float4*)ap;
        float4 v1 = *(const float4*)(ap + 4);
        float vv[8] = {v0.x,v0.y,v0.z,v0.w,v1.x,v1.y,v1.z,v1.w};
#pragma unroll
        for (int j = 0; j < 8; j++){
          ushort_t hb = f2b(vv[j]);
          float hf = __uint_as_float((uint_t)hb << 16);
          AHI[ks][j] = (short)hb;
          ALO[ks][j] = (short)f2b(vv[j] - hf);
        }
      }
    }
#pragma unroll
    for (int half = 0; half < 2; half++){
      __syncthreads();
      {
        const int cnt4 = half ? 2304 : 2048;                 // uint4 count
        const uint4* src = (const uint4*)w1bp + (half ? 2048 : 0);
        uint4* dst = (uint4*)ldsB;
        for (int i = tid; i < cnt4; i += 512) dst[i] = src[i];
      }
      __syncthreads();
      if (!act) continue;
      const int nt = half ? 9 : 8;
      floatx4 c[9];
#pragma unroll
      for (int i = 0; i < 9; i++) c[i] = (floatx4){0.f,0.f,0.f,0.f};
#pragma unroll
      for (int ks = 0; ks < 4; ks++){
        for (int i = 0; i < nt; i++){
          short8 b = *(const short8*)&ldsB[(size_t)((i*4 + ks)*64 + lane)*8];
          c[i] = __builtin_amdgcn_mfma_f32_16x16x32_bf16(AHI[ks], b, c[i], 0, 0, 0);
        }
        if (half){
          short8 b = *(const short8*)&ldsB[(size_t)((8*4 + ks)*64 + lane)*8];
          c[8] = __builtin_amdgcn_mfma_f32_16x16x32_bf16(ALO[ks], b, c[8], 0, 0, 0);
        }
      }
      const int m0 = half ? 2 : 0;
#pragma unroll
      for (int i = 0; i < 4; i++){
        const int r = row0 + quad*4 + i;
        if (r >= N) continue;
#pragma unroll
        for (int dm = 0; dm < 2; dm++){
          int u = 0;
          u = __builtin_amdgcn_cvt_pk_fp8_f32(c[0*2+dm][i], c[1*2+dm][i], u, false);
          u = __builtin_amdgcn_cvt_pk_fp8_f32(c[2*2+dm][i], c[3*2+dm][i], u, true);
          z8[(size_t)r*64 + (m0+dm)*16 + l16] = (uint_t)u;
        }
        if (half){
          const float sv = c[8][i];
          if (l16 < 4) s1s[r*4 + l16] = sv;
          else if (l16 < 8) s1d[r*4 + (l16 - 4)] = sv;
        }
      }
    }
  } else if (id < Gg + Gs){
    // ---- dst scatter role: rank-based, NO atomics; csr + edge id
    const int i = (id - Gg)*512 + tid;
    if (i < E){
      const int d = dstI[i];
      const uint_t u = (uint_t)rk[i];
      const int pD = base8[(size_t)(u >> 28)*PAD + d] + (int)(u & 0x0FFFFFFFu);
      csr[pD]    = srcI[i];
      csrEid[pD] = i;
    }
  } else if (id < Gg + Gs + Gh){
    // ---- src histogram role (R26): overlaps the LLC-RMW unit with compute
    const int i = (id - Gg - Gs)*512 + tid;
    if (i < E){
      const unsigned xcd = xcc_id();
      int s = srcI[i];
      int rs = __hip_atomic_fetch_add(&degS8[(size_t)xcd*PAD + s], 1,
                                      __ATOMIC_RELAXED, __HIP_MEMORY_SCOPE_WORKGROUP);
      rkS[i] = (int)((xcd << 28) | (unsigned)rs);
    }
  } else {
    // frac role: streaming cnt-weighted sum over contiguous h rows.
    float (*red)[384] = (float(*)[384])smem;
    const int wave = tid >> 6, lane = tid & 63;
    const int g = lane >> 5, li = lane & 31;
    const int Gf = G - Gg - Gs - Gh;
    const int stream0 = (id - Gg - Gs - Gh)*16 + wave*2 + g;
    const int step16 = Gf * 16;
    float4 a0 = {0,0,0,0}, a1 = {0,0,0,0}, a2 = {0,0,0,0};
    for (int n = stream0; n < N; n += step16){
      const float w0 = (float)cnt[n*3];
      const float w1 = (float)cnt[n*3+1];
      const float w2 = (float)cnt[n*3+2];
      float4 v = *(const float4*)&h[(size_t)n*128 + li*4];
      a0.x += w0*v.x; a0.y += w0*v.y; a0.z += w0*v.z; a0.w += w0*v.w;
      a1.x += w1*v.x; a1.y += w1*v.y; a1.z += w1*v.z; a1.w += w1*v.w;
      a2.x += w2*v.x; a2.y += w2*v.y; a2.z += w2*v.z; a2.w += w2*v.w;
    }
    const int w16 = wave*2 + g;
    *(float4*)&red[w16][0*128 + li*4] = a0;
    *(float4*)&red[w16][1*128 + li*4] = a1;
    *(float4*)&red[w16][2*128 + li*4] = a2;
    __syncthreads();
    for (int i = tid; i < 384; i += 512){
      float v = 0.f;
#pragma unroll
      for (int w = 0; w < 16; w++) v += red[w][i];
      atomicAdd(&accFrac[i], v);
    }
  }
}

// ---------------- layer1 GAT aggregation + ELU -> hneib bf16 + fused layer2 scores
// dbase param — launched 2x over disjoint dst halves (keeps table unmasked).
__global__ __launch_bounds__(256) void k_gat1(
    const uint_t* __restrict__ z8, const float* __restrict__ s1src, const float* __restrict__ s1dst,
    const int* __restrict__ rowptr, const int* __restrict__ csr, const float* __restrict__ v2,
    uint_t* __restrict__ hneib, float* __restrict__ s2s, float* __restrict__ s2d, int N, int dbase)
{
  __shared__ int   sbuf[4][CAP];                 // s*64 (dword offset into z8)
  __shared__ __align__(16) float4 ebuf[4][CAP];
  __shared__ float v2s[512];
  const int tid = threadIdx.x;
  v2s[tid] = v2[tid];
  v2s[tid + 256] = v2[tid + 256];
  __syncthreads();
  const int wave = tid >> 6, lane = tid & 63;
  const int dst = (dbase + blockIdx.x)*4 + wave;
  if (dst >= N) return;
  const int beg = rowptr[dst];
  const int deg = rowptr[dst+1] - beg;
  const float4 sd = *(const float4*)&s1dst[dst*4];
  float t0=0.f,t1=0.f,t2=0.f,t3=0.f;
  for (int j = lane; j < deg; j += 64){
    int s = csr[beg+j];
    float4 sv = *(const float4*)&s1src[s*4];
    float4 a;
    a.x = __expf(lrelu(sv.x+sd.x)); a.y = __expf(lrelu(sv.y+sd.y));
    a.z = __expf(lrelu(sv.z+sd.z)); a.w = __expf(lrelu(sv.w+sd.w));
    if (j < CAP){ sbuf[wave][j] = s*64; ebuf[wave][j] = a; }
    t0 += a.x; t1 += a.y; t2 += a.z; t3 += a.w;
  }
  const float inv[4] = {1.f/wred_sum(t0), 1.f/wred_sum(t1), 1.f/wred_sum(t2), 1.f/wred_sum(t3)};
  const int eh = lane >> 5, li = lane & 31;
  floatx2 c00 = {0.f,0.f}, c01 = {0.f,0.f}, c10 = {0.f,0.f}, c11 = {0.f,0.f};
  if (deg <= CAP){
    const int j0 = (eh < deg) ? eh : 0;
    int offc = sbuf[wave][j0];
    float4 alc = ebuf[wave][j0];
    uint2 uc = *((const uint2*)(z8 + offc) + li);
    for (int jj = 0; jj + 2 <= deg; jj += 2){
      const int jn = jj + 2 + eh;
      const int jnc = (jn < deg) ? jn : (jj + eh);
      const int offn = sbuf[wave][jnc];
      const float4 aln = ebuf[wave][jnc];
      const uint2 un = *((const uint2*)(z8 + offn) + li);   // issue before use of uc
      agg8(uc, alc, c00, c01, c10, c11);
      uc = un; alc = aln;
    }
    if ((deg & 1) && eh == 0)
      agg8(uc, alc, c00, c01, c10, c11);
  } else {
    for (int jj = 0; jj < deg; jj += 2){
      const int j = jj + eh;
      const bool v = j < deg;
      const int jc = v ? j : jj;
      int off; float4 al;
      if (jc < CAP){ off = sbuf[wave][jc]; al = ebuf[wave][jc]; }
      else {
        int s = csr[beg+jc];
        off = s*64;
        float4 sv = *(const float4*)&s1src[s*4];
        al.x = __expf(lrelu(sv.x+sd.x)); al.y = __expf(lrelu(sv.y+sd.y));
        al.z = __expf(lrelu(sv.z+sd.z)); al.w = __expf(lrelu(sv.w+sd.w));
      }
      if (!v){ al.x=0.f; al.y=0.f; al.z=0.f; al.w=0.f; }
      uint2 u = *((const uint2*)(z8 + off) + li);
      agg8(u, al, c00, c01, c10, c11);
    }
  }
  float acc[2][4] = {{c00.x, c00.y, c01.x, c01.y},
                     {c10.x, c10.y, c11.x, c11.y}};
#pragma unroll
  for (int k = 0; k < 2; k++)
#pragma unroll
    for (int hh = 0; hh < 4; hh++) acc[k][hh] += __shfl_xor(acc[k][hh], 32, 64);
  const float* vv = &v2s[eh*256];
  float p = 0.f;
#pragma unroll
  for (int hh = 0; hh < 4; hh++){
    float e0 = acc[0][hh]*inv[hh]; e0 = e0 > 0.f ? e0 : expm1f(e0);
    float e1 = acc[1][hh]*inv[hh]; e1 = e1 > 0.f ? e1 : expm1f(e1);
    p += e0 * vv[hh*64 + 2*li] + e1 * vv[hh*64 + 2*li + 1];
    if ((hh >> 1) == eh)
      hneib[(size_t)dst*128 + hh*32 + li] = (uint_t)f2b(e0) | ((uint_t)f2b(e1) << 16);
  }
#pragma unroll
  for (int o = 1; o < 32; o <<= 1) p += __shfl_xor(p, o, 64);
  if (lane == 0)  s2s[dst] = p;
  if (lane == 32) s2d[dst] = p;
}

// ---------------- layer2 alpha-weights: atomic-free; pS derived in-kernel (R26)
__global__ __launch_bounds__(256) void k_aw2(
    const float* __restrict__ s2s, const float* __restrict__ s2d,
    const int* __restrict__ rowptr, const int* __restrict__ csr,
    const int* __restrict__ csrEid, const int* __restrict__ rkS,
    const int* __restrict__ baseS8, int PAD,
    float* __restrict__ alphaCSC, int N)
{
  __shared__ int   sbuf[4][CAP];
  __shared__ float ebuf[4][CAP];
  const int wave = threadIdx.x >> 6, lane = threadIdx.x & 63;
  const int dst = blockIdx.x*4 + wave;
  if (dst >= N) return;
  const int beg = rowptr[dst], deg = rowptr[dst+1] - beg;
  const float sd = s2d[dst];
  float ts = 0.f;
  for (int j = lane; j < deg; j += 64){
    int s = csr[beg+j];
    float a = __expf(lrelu(s2s[s] + sd));
    if (j < CAP){ sbuf[wave][j] = s; ebuf[wave][j] = a; }
    ts += a;
  }
  const float inv = 1.f/wred_sum(ts);
  for (int j = lane; j < deg; j += 64){
    int s; float a;
    if (j < CAP){ s = sbuf[wave][j]; a = ebuf[wave][j]; }
    else { s = csr[beg+j]; a = __expf(lrelu(s2s[s] + sd)); }
    const int eid = csrEid[beg+j];                 // coalesced
    const uint_t u = (uint_t)rkS[eid];             // random 4B gather
    const int pS = baseS8[(size_t)(u >> 28)*PAD + s] + (int)(u & 0x0FFFFFFFu);
    alphaCSC[pS] = a * inv;                        // plain random 4B store
  }
}

// ---------------- per-src segmented sum: wsrc[n] = Σ alphaCSC[rowptrS[n]..)
__global__ __launch_bounds__(256) void k_wsum(const float* __restrict__ alphaCSC,
    const int* __restrict__ rowptrS, float* __restrict__ wsrc, int N)
{
  const int n = blockIdx.x*256 + threadIdx.x;
  if (n >= N) return;
  const int b = rowptrS[n], e = rowptrS[n+1];
  float s = 0.f;
  for (int k = b; k < e; k++) s += alphaCSC[k];
  wsrc[n] = s;
}

// ---------------- weighted hnei sum (coalesced)
__global__ __launch_bounds__(256) void k_hsum(const uint_t* __restrict__ hneib,
    const float* __restrict__ wsrc, float* __restrict__ acc256, int N)
{
  __shared__ float pr[512];
  const int t = threadIdx.x;
  const int h2 = t >> 7, p = t & 127;
  float a0 = 0.f, a1 = 0.f;
  const int step = gridDim.x * 2;
  for (int n = blockIdx.x*2 + h2; n < N; n += step){
    float wn = wsrc[n];
    uint_t u = hneib[(size_t)n*128 + p];
    a0 += wn * b2f_lo(u);
    a1 += wn * b2f_hi(u);
  }
  pr[h2*256 + 2*p]     = a0;
  pr[h2*256 + 2*p + 1] = a1;
  __syncthreads();
  float v = pr[t] + pr[256 + t];
  int pp = t >> 1;
  int d = (pp >> 5)*64 + 2*(pp & 31) + (t & 1);
  atomicAdd(&acc256[d], v);
}

// ---------------- finalize
__global__ __launch_bounds__(256) void k_finalize(const float* __restrict__ acc256,
    const float* __restrict__ accFrac, const float* __restrict__ W2,
    const float* __restrict__ frw, const float* __restrict__ frf,
    const float* __restrict__ fc2, float* __restrict__ out, float invN)
{
  __shared__ float mh[256], nei[64], g[384], mm[192], hfrac[64];
  int t = threadIdx.x;
  mh[t] = acc256[t] * invN;
  for (int i = t; i < 384; i += 256) g[i] = accFrac[i] * invN;
  __syncthreads();
  if (t < 64){
    float s = 0.f;
    for (int k = 0; k < 256; k++) s += W2[t*256 + k] * mh[k];
    nei[t] = s;
  }
  for (int i = t; i < 192; i += 256){
    int s = i >> 6, d = i & 63;
    const float* w = frw + (size_t)(s*64 + d)*128;
    const float* gs = g + s*128;
    float sum = 0.f;
    for (int k = 0; k < 128; k++) sum += gs[k]*w[k];
    mm[i] = sum;
  }
  __syncthreads();
  if (t < 64){
    float s = 0.f;
    for (int k = 0; k < 192; k++) s += mm[k]*frf[t*192 + k];
    hfrac[t] = s;
  }
  __syncthreads();
  if (t < 64){
    float o = 0.f;
    for (int k = 0; k < 64; k++)
      o += fc2[t*128 + k]*nei[k] + fc2[t*128 + 64 + k]*hfrac[k];
    out[t] = o;
  }
}

extern "C" void kernel_launch(void* const* d_in, const int* in_sizes, int n_in,
                              void* d_out, int out_size, void* d_ws, size_t ws_size,
                              hipStream_t stream)
{
  const float* h    = (const float*)d_in[0];
  const int*   srcI = (const int*)  d_in[1];
  const int*   dstI = (const int*)  d_in[2];
  const int*   fcm  = (const int*)  d_in[3];
  const float* l1fc = (const float*)d_in[4];
  const float* l1at = (const float*)d_in[5];
  const float* l2fc = (const float*)d_in[6];
  const float* l2at = (const float*)d_in[7];
  const float* frw  = (const float*)d_in[8];
  const float* frf  = (const float*)d_in[9];
  const float* fc2  = (const float*)d_in[10];
  float* out = (float*)d_out;
  (void)n_in; (void)out_size; (void)ws_size;

  const int N = in_sizes[0] / 128;
  const int E = in_sizes[1];
  const int B = (N + 256) / 256;     // ceil((N+1)/256) so rowptr[N] is covered
  const int PAD = B * 256;

  char* w = (char*)d_ws;
  size_t off = 0;
  auto alloc = [&](size_t bytes) -> char* {
    char* p = w + off; off = (off + bytes + 255) & ~(size_t)255; return p;
  };
  uint_t* z8    = (uint_t*)alloc((size_t)N*64*4);    // 25.6 MB fp8 z
  uint_t* hneib = (uint_t*)alloc((size_t)N*128*4);   // 51.2 MB packed bf16 hnei
  int*    rk    = (int*)hneib;                       // dst ranks alias hneib
                                                     // (read by mega, before gat1)
  float* s1s  = (float*)alloc((size_t)N*4*4);
  float* s1d  = (float*)alloc((size_t)N*4*4);
  float* s2s  = (float*)alloc((size_t)N*4);
  float* s2d  = (float*)alloc((size_t)N*4);
  // ---- zeroed region (one memset): deg8, degS8, cnt, acc256, accFrac
  int*   deg8    = (int*)  alloc((size_t)8*PAD*4);   // XCD-local dst histograms
  int*   degS8   = (int*)  alloc((size_t)8*PAD*4);   // XCD-local src histograms
  int*   cnt     = (int*)  alloc((size_t)N*3*4);     // fcm occurrence histogram
  float* acc256  = (float*)alloc(256*4);
  float* accFrac = (float*)alloc(384*4);
  const size_t zbytes = (size_t)((char*)accFrac + 384*4 - (char*)deg8);
  // ---- rest
  int*   rowptr  = (int*)alloc((size_t)PAD*4);
  int*   rowptrS = (int*)alloc((size_t)PAD*4);
  int*   base8   = (int*)alloc((size_t)8*PAD*4);
  int*   baseS8  = (int*)alloc((size_t)8*PAD*4);
  int*   partD   = (int*)alloc(512*4);
  int*   partS   = (int*)alloc(512*4);
  int*   csr     = (int*)alloc((size_t)E*4);
  int*   csrEid  = (int*)alloc((size_t)E*4);
  int*   rkS     = (int*)alloc((size_t)E*4);         // own buffer (lives until aw2)
  float* alphaCSC= (float*)alloc((size_t)E*4);       // written 1x per slot, no init
  float* wsrc    = (float*)alloc((size_t)N*4);
  ushort_t* w1bp = (ushort_t*)alloc(34816*2);   // 16 z-tiles (permuted) + score tile
  float* v2     = (float*)alloc(512*4);

  hipMemsetAsync(deg8, 0, zbytes, stream);

  hipLaunchKernelGGL(k_prep,  dim3(130 + 512), dim3(256), 0, stream,
                     l1fc, l2fc, l1at, l2at, dstI, E, fcm, 3*N, cnt, w1bp, v2,
                     deg8, rk, PAD);
  // dst-side scans
  hipLaunchKernelGGL(k_scan1, dim3(B), dim3(256), 0, stream, deg8, partD, PAD);
  hipLaunchKernelGGL(k_scan2, dim3(1), dim3(512), 0, stream, partD, B);
  hipLaunchKernelGGL(k_scan3, dim3(B), dim3(256), 0, stream, deg8, partD,
                     rowptr, base8, PAD);

  const int Gg = (N + 127) / 128;
  const int Gs = (E + 511) / 512;
  const int Gh = (E + 511) / 512;
  const int Gf = 512;
  const int G  = Gg + Gs + Gh + Gf;
  int step = (int)(G * 0.618) | 1;
  auto gcd = [](int a, int b){ while (b){ int t = a % b; a = b; b = t; } return a; };
  while (gcd(step, G) != 1) step += 2;

  hipLaunchKernelGGL(k_mega,  dim3(G), dim3(512), 0, stream,
                     h, w1bp, z8, s1s, s1d, N,
                     srcI, dstI, rk, base8, PAD, csr, csrEid, degS8, rkS, E,
                     Gg, Gs, Gh, G, step, cnt, accFrac);
  // src-side scans (hidden behind gat1's runtime)
  hipLaunchKernelGGL(k_scan1, dim3(B), dim3(256), 0, stream, degS8, partS, PAD);
  hipLaunchKernelGGL(k_scan2, dim3(1), dim3(512), 0, stream, partS, B);
  hipLaunchKernelGGL(k_scan3, dim3(B), dim3(256), 0, stream, degS8, partS,
                     rowptrS, baseS8, PAD);

  const int nb  = (N + 3) / 4;
  const int nb1 = nb / 2;
  hipLaunchKernelGGL(k_gat1,  dim3(nb1),      dim3(256), 0, stream,
                     z8, s1s, s1d, rowptr, csr, v2, hneib, s2s, s2d, N, 0);
  hipLaunchKernelGGL(k_gat1,  dim3(nb - nb1), dim3(256), 0, stream,
                     z8, s1s, s1d, rowptr, csr, v2, hneib, s2s, s2d, N, nb1);
  hipLaunchKernelGGL(k_aw2,   dim3(nb),       dim3(256), 0, stream,
                     s2s, s2d, rowptr, csr, csrEid, rkS, baseS8, PAD, alphaCSC, N);
  hipLaunchKernelGGL(k_wsum,  dim3((N+255)/256), dim3(256), 0, stream,
                     alphaCSC, rowptrS, wsrc, N);
  hipLaunchKernelGGL(k_hsum,  dim3(608),      dim3(256), 0, stream,
                     hneib, wsrc, acc256, N);
  hipLaunchKernelGGL(k_finalize, dim3(1),     dim3(256), 0, stream,
                     acc256, accFrac, l2fc, frw, frf, fc2, out, 1.0f/(float)N);
}

// Round 14
// 513.740 us; speedup vs baseline: 1.1118x; 1.0945x over previous
//
#include <hip/hip_runtime.h>
#include <math.h>

// GAT pipeline. Layer2 collapsed (w_s = Σ α over src edges); z fp8 e4m3; MFMA
// GEMM1 with f32 score tile. Mega-kernel (gemm+scatter+frac), striped roles.
// R17: frac gather eliminated (cnt histogram). 526.3µs.
// R18-R20: k_gat1 traffic shaping — DEAD END (random-gather LLC ceiling,
//      ~117µs floor; FETCH invariant at 243MB across all variants).
// R23: XCD-local atomics + rank-based atomic-free csr scatter. 515.3µs BEST.
// R24: diag split: aw2 86µs, WRITE 53MB unchanged -> atomics run at the
//      memory-side LLC ~20-25G/s REGARDLESS of scope hints.
// R25: CSC plain-store aw2 + 2nd histogram in prep -> prep 150µs, 571. DEAD.
// R26: 2nd histogram striped into mega -> mega 142µs, WRITE 195MB, 562. DEAD.
//      Law (3x measured): any 1.7M-edge global histogram costs ~55-85µs at
//      the LLC RMW ceiling wherever it is placed; CSC spends one histogram
//      (~55-85) to save aw2's ~40 -> structurally net-negative.
// R27: RESTORE R23 exactly (best verified). Cost structure at HW ceilings:
//      gat1 117 (LLC random-gather), aw2 86 (fp RMW), mega ~88 (scatter
//      line-dirtying, atomic-free), prep ~70 (dst hist RMW, first kernel).

#define CAP 128

typedef unsigned int  uint_t;
typedef unsigned short ushort_t;
typedef __attribute__((ext_vector_type(8))) short short8;
typedef __attribute__((ext_vector_type(4))) float floatx4;
typedef __attribute__((ext_vector_type(2))) float floatx2;

__device__ __forceinline__ unsigned xcc_id(){
  unsigned x;
  asm volatile("s_getreg_b32 %0, hwreg(HW_REG_XCC_ID)" : "=s"(x));
  return x & 7u;
}
__device__ __forceinline__ float wred_sum(float v){
#pragma unroll
  for (int o = 1; o < 64; o <<= 1) v += __shfl_xor(v, o, 64);
  return v;
}
__device__ __forceinline__ float lrelu(float x){ return x >= 0.f ? x : 0.01f*x; }
__device__ __forceinline__ ushort_t f2b(float f){
  uint_t u = __float_as_uint(f);
  u = (u + 0x7FFFu + ((u >> 16) & 1u)) >> 16;   // RNE
  return (ushort_t)u;
}
__device__ __forceinline__ float b2f_lo(uint_t w){ return __uint_as_float(w << 16); }
__device__ __forceinline__ float b2f_hi(uint_t w){ return __uint_as_float(w & 0xFFFF0000u); }

// 8 fp8 values (uint2) x per-head alpha (float4) -> packed float2 accumulators
__device__ __forceinline__ void agg8(uint2 u, float4 al,
    floatx2& c00, floatx2& c01, floatx2& c10, floatx2& c11){
  floatx2 p0 = __builtin_amdgcn_cvt_pk_f32_fp8(u.x, false);
  floatx2 p1 = __builtin_amdgcn_cvt_pk_f32_fp8(u.x, true);
  floatx2 p2 = __builtin_amdgcn_cvt_pk_f32_fp8(u.y, false);
  floatx2 p3 = __builtin_amdgcn_cvt_pk_f32_fp8(u.y, true);
  floatx2 aXY = {al.x, al.y}, aZW = {al.z, al.w};
  c00 += aXY * p0;
  c01 += aZW * p1;
  c10 += aXY * p2;
  c11 += aZW * p3;
}

// ---------------- prep: W1 pack, score tile, v2, + hist (deg8 XCD-local + rank, cnt)
__global__ void k_prep(const float* __restrict__ W1, const float* __restrict__ W2,
                       const float* __restrict__ a1, const float* __restrict__ a2,
                       const int* __restrict__ dstI, int E,
                       const int* __restrict__ fcm, int N3, int* __restrict__ cnt,
                       ushort_t* __restrict__ w1bp, float* __restrict__ v2,
                       int* __restrict__ deg8, int* __restrict__ rk, int PAD){
  __shared__ float v[8][128];
  const int bx = blockIdx.x, t = threadIdx.x;
  if (bx < 128){
    int idx = bx*256 + t;
    int j = idx & 7, lane = (idx >> 3) & 63, ks = (idx >> 9) & 3, tt = idx >> 11;
    int n = tt*16 + (lane & 15), k = ks*32 + (lane >> 4)*8 + j;
    int hh = tt >> 2, m = tt & 3;
    int pt = (m < 2) ? (hh*2 + m) : (8 + hh*2 + (m - 2));
    w1bp[((pt*4 + ks)*64 + lane)*8 + j] = f2b(W1[n*128 + k]);
  } else if (bx == 128){
    for (int o = t; o < 1024; o += 256){
      int col = o >> 7, k = o & 127, hh = col & 3, off = (col >> 2)*64;
      float s = 0.f;
      for (int n = 0; n < 64; n++) s += a1[hh*128 + off + n] * W1[(hh*64 + n)*128 + k];
      v[col][k] = s;
    }
    __syncthreads();
    for (int idx = t; idx < 2048; idx += 256){
      int j = idx & 7, lane = (idx >> 3) & 63, ks = idx >> 9;
      int col = lane & 15, k = ks*32 + (lane >> 4)*8 + j;
      w1bp[32768 + idx] = (col < 8) ? f2b(v[col][k]) : (ushort_t)0;   // packed tile 16
    }
  } else if (bx == 129){
    float s0 = 0.f, s1 = 0.f;
    for (int j = 0; j < 64; j++){
      float wjk = W2[j*256 + t];
      s0 += wjk * a2[j];
      s1 += wjk * a2[64 + j];
    }
    v2[t] = s0; v2[256 + t] = s1;
  } else {
    const int nb = gridDim.x - 130;
    const unsigned xcd = xcc_id();
    int* myDeg = deg8 + (size_t)xcd * PAD;
    for (int i = (bx-130)*256 + t; i < E; i += nb*256){
      int d = dstI[i];
      int r = __hip_atomic_fetch_add(&myDeg[d], 1, __ATOMIC_RELAXED,
                                     __HIP_MEMORY_SCOPE_WORKGROUP);
      rk[i] = (int)((xcd << 28) | (unsigned)r);
    }
    for (int i = (bx-130)*256 + t; i < N3; i += nb*256){
      int v3 = fcm[i];
      atomicAdd(&cnt[v3*3 + (i % 3)], 1);     // 300k only
    }
  }
}

// ---------------- scans
__global__ __launch_bounds__(256) void k_scan1(const int* __restrict__ deg8,
    int* __restrict__ part, int PAD){
  __shared__ int tmp[256];
  int t = threadIdx.x, i = blockIdx.x*256 + t;
  int v = 0;
#pragma unroll
  for (int x = 0; x < 8; x++) v += deg8[(size_t)x*PAD + i];
  tmp[t] = v;
  __syncthreads();
  for (int off = 128; off > 0; off >>= 1){
    if (t < off) tmp[t] += tmp[t+off];
    __syncthreads();
  }
  if (t == 0) part[blockIdx.x] = tmp[0];
}
__global__ __launch_bounds__(512) void k_scan2(int* __restrict__ part, int B){
  __shared__ int tmp[512];
  int t = threadIdx.x;
  int v = (t < B) ? part[t] : 0;
  tmp[t] = v; __syncthreads();
  for (int off = 1; off < 512; off <<= 1){
    int x = (t >= off) ? tmp[t-off] : 0;
    __syncthreads();
    tmp[t] += x;
    __syncthreads();
  }
  if (t < B) part[t] = tmp[t] - v;   // exclusive
}
// scan3: rowptr = exclusive scan of Σx deg8; base8[x][i] = per-XCD sub-range start
__global__ __launch_bounds__(256) void k_scan3(const int* __restrict__ deg8,
    const int* __restrict__ part, int* __restrict__ rowptr,
    int* __restrict__ base8, int PAD){
  __shared__ int tmp[256];
  int t = threadIdx.x, i = blockIdx.x*256 + t;
  int d8[8]; int v = 0;
#pragma unroll
  for (int x = 0; x < 8; x++){ d8[x] = deg8[(size_t)x*PAD + i]; v += d8[x]; }
  tmp[t] = v; __syncthreads();
  for (int off = 1; off < 256; off <<= 1){
    int x = (t >= off) ? tmp[t-off] : 0;
    __syncthreads();
    tmp[t] += x;
    __syncthreads();
  }
  int excl = tmp[t] - v + part[blockIdx.x];
  rowptr[i] = excl;
  int run = excl;
#pragma unroll
  for (int x = 0; x < 8; x++){ base8[(size_t)x*PAD + i] = run; run += d8[x]; }
}

// ---------------- MEGA (striped roles): gemm + scatter(atomic-free) + frac
__global__ __launch_bounds__(512, 4) void k_mega(const float* __restrict__ h,
    const ushort_t* __restrict__ w1bp,
    uint_t* __restrict__ z8, float* __restrict__ s1s, float* __restrict__ s1d, int N,
    const int* __restrict__ srcI, const int* __restrict__ dstI,
    const int* __restrict__ rk, const int* __restrict__ base8, int PAD,
    int* __restrict__ csr, int E,
    int Gg, int Gs, int G, int step,
    const int* __restrict__ cnt, float* __restrict__ accFrac)
{
  static __shared__ __align__(16) char smem[36864];
  const int tid = threadIdx.x;
  const int id = (int)(((unsigned long long)blockIdx.x * (unsigned)step) % (unsigned)G);
  if (id < Gg){
    ushort_t* ldsB = (ushort_t*)smem;
    const int wave = tid >> 6, lane = tid & 63;
    const int quad = lane >> 4, l16 = lane & 15;
    const int row0 = id*128 + wave*16;
    const bool act = row0 < N;
    const int ar = act ? ((row0 + l16 < N) ? (row0 + l16) : (N - 1)) : 0;
    short8 AHI[4], ALO[4];
    if (act){
#pragma unroll
      for (int ks = 0; ks < 4; ks++){
        const float* ap = &h[(size_t)ar*128 + ks*32 + quad*8];
        float4 v0 = *(const float4*)ap;
        float4 v1 = *(const float4*)(ap + 4);
        float vv[8] = {v0.x,v0.y,v0.z,v0.w,v1.x,v1.y,v1.z,v1.w};
#pragma unroll
        for (int j = 0; j < 8; j++){
          ushort_t hb = f2b(vv[j]);
          float hf = __uint_as_float((uint_t)hb << 16);
          AHI[ks][j] = (short)hb;
          ALO[ks][j] = (short)f2b(vv[j] - hf);
        }
      }
    }
#pragma unroll
    for (int half = 0; half < 2; half++){
      __syncthreads();
      {
        const int cnt4 = half ? 2304 : 2048;                 // uint4 count
        const uint4* src = (const uint4*)w1bp + (half ? 2048 : 0);
        uint4* dst = (uint4*)ldsB;
        for (int i = tid; i < cnt4; i += 512) dst[i] = src[i];
      }
      __syncthreads();
      if (!act) continue;
      const int nt = half ? 9 : 8;
      floatx4 c[9];
#pragma unroll
      for (int i = 0; i < 9; i++) c[i] = (floatx4){0.f,0.f,0.f,0.f};
#pragma unroll
      for (int ks = 0; ks < 4; ks++){
        for (int i = 0; i < nt; i++){
          short8 b = *(const short8*)&ldsB[(size_t)((i*4 + ks)*64 + lane)*8];
          c[i] = __builtin_amdgcn_mfma_f32_16x16x32_bf16(AHI[ks], b, c[i], 0, 0, 0);
        }
        if (half){
          short8 b = *(const short8*)&ldsB[(size_t)((8*4 + ks)*64 + lane)*8];
          c[8] = __builtin_amdgcn_mfma_f32_16x16x32_bf16(ALO[ks], b, c[8], 0, 0, 0);
        }
      }
      const int m0 = half ? 2 : 0;
#pragma unroll
      for (int i = 0; i < 4; i++){
        const int r = row0 + quad*4 + i;
        if (r >= N) continue;
#pragma unroll
        for (int dm = 0; dm < 2; dm++){
          int u = 0;
          u = __builtin_amdgcn_cvt_pk_fp8_f32(c[0*2+dm][i], c[1*2+dm][i], u, false);
          u = __builtin_amdgcn_cvt_pk_fp8_f32(c[2*2+dm][i], c[3*2+dm][i], u, true);
          z8[(size_t)r*64 + (m0+dm)*16 + l16] = (uint_t)u;
        }
        if (half){
          const float sv = c[8][i];
          if (l16 < 4) s1s[r*4 + l16] = sv;
          else if (l16 < 8) s1d[r*4 + (l16 - 4)] = sv;
        }
      }
    }
  } else if (id < Gg + Gs){
    // ---- scatter role: rank-based, NO atomics
    const int i = (id - Gg)*512 + tid;
    if (i < E){
      const int d = dstI[i];
      const uint_t u = (uint_t)rk[i];
      const int p = base8[(size_t)(u >> 28)*PAD + d] + (int)(u & 0x0FFFFFFFu);
      csr[p] = srcI[i];
    }
  } else {
    // frac role: streaming cnt-weighted sum over contiguous h rows.
    float (*red)[384] = (float(*)[384])smem;
    const int wave = tid >> 6, lane = tid & 63;
    const int g = lane >> 5, li = lane & 31;
    const int Gf = G - Gg - Gs;
    const int stream0 = (id - Gg - Gs)*16 + wave*2 + g;
    const int step16 = Gf * 16;
    float4 a0 = {0,0,0,0}, a1 = {0,0,0,0}, a2 = {0,0,0,0};
    for (int n = stream0; n < N; n += step16){
      const float w0 = (float)cnt[n*3];
      const float w1 = (float)cnt[n*3+1];
      const float w2 = (float)cnt[n*3+2];
      float4 v = *(const float4*)&h[(size_t)n*128 + li*4];
      a0.x += w0*v.x; a0.y += w0*v.y; a0.z += w0*v.z; a0.w += w0*v.w;
      a1.x += w1*v.x; a1.y += w1*v.y; a1.z += w1*v.z; a1.w += w1*v.w;
      a2.x += w2*v.x; a2.y += w2*v.y; a2.z += w2*v.z; a2.w += w2*v.w;
    }
    const int w16 = wave*2 + g;
    *(float4*)&red[w16][0*128 + li*4] = a0;
    *(float4*)&red[w16][1*128 + li*4] = a1;
    *(float4*)&red[w16][2*128 + li*4] = a2;
    __syncthreads();
    for (int i = tid; i < 384; i += 512){
      float v = 0.f;
#pragma unroll
      for (int w = 0; w < 16; w++) v += red[w][i];
      atomicAdd(&accFrac[i], v);
    }
  }
}

// ---------------- layer1 GAT aggregation + ELU -> hneib bf16 + fused layer2 scores
__global__ __launch_bounds__(256) void k_gat1(
    const uint_t* __restrict__ z8, const float* __restrict__ s1src, const float* __restrict__ s1dst,
    const int* __restrict__ rowptr, const int* __restrict__ csr, const float* __restrict__ v2,
    uint_t* __restrict__ hneib, float* __restrict__ s2s, float* __restrict__ s2d, int N)
{
  __shared__ int   sbuf[4][CAP];                 // s*64 (dword offset into z8)
  __shared__ __align__(16) float4 ebuf[4][CAP];
  __shared__ float v2s[512];
  const int tid = threadIdx.x;
  v2s[tid] = v2[tid];
  v2s[tid + 256] = v2[tid + 256];
  __syncthreads();
  const int wave = tid >> 6, lane = tid & 63;
  const int dst = blockIdx.x*4 + wave;
  if (dst >= N) return;
  const int beg = rowptr[dst];
  const int deg = rowptr[dst+1] - beg;
  const float4 sd = *(const float4*)&s1dst[dst*4];
  float t0=0.f,t1=0.f,t2=0.f,t3=0.f;
  for (int j = lane; j < deg; j += 64){
    int s = csr[beg+j];
    float4 sv = *(const float4*)&s1src[s*4];
    float4 a;
    a.x = __expf(lrelu(sv.x+sd.x)); a.y = __expf(lrelu(sv.y+sd.y));
    a.z = __expf(lrelu(sv.z+sd.z)); a.w = __expf(lrelu(sv.w+sd.w));
    if (j < CAP){ sbuf[wave][j] = s*64; ebuf[wave][j] = a; }
    t0 += a.x; t1 += a.y; t2 += a.z; t3 += a.w;
  }
  const float inv[4] = {1.f/wred_sum(t0), 1.f/wred_sum(t1), 1.f/wred_sum(t2), 1.f/wred_sum(t3)};
  const int eh = lane >> 5, li = lane & 31;
  floatx2 c00 = {0.f,0.f}, c01 = {0.f,0.f}, c10 = {0.f,0.f}, c11 = {0.f,0.f};
  if (deg <= CAP){
    const int j0 = (eh < deg) ? eh : 0;
    int offc = sbuf[wave][j0];
    float4 alc = ebuf[wave][j0];
    uint2 uc = *((const uint2*)(z8 + offc) + li);
    for (int jj = 0; jj + 2 <= deg; jj += 2){
      const int jn = jj + 2 + eh;
      const int jnc = (jn < deg) ? jn : (jj + eh);
      const int offn = sbuf[wave][jnc];
      const float4 aln = ebuf[wave][jnc];
      const uint2 un = *((const uint2*)(z8 + offn) + li);   // issue before use of uc
      agg8(uc, alc, c00, c01, c10, c11);
      uc = un; alc = aln;
    }
    if ((deg & 1) && eh == 0)
      agg8(uc, alc, c00, c01, c10, c11);
  } else {
    for (int jj = 0; jj < deg; jj += 2){
      const int j = jj + eh;
      const bool v = j < deg;
      const int jc = v ? j : jj;
      int off; float4 al;
      if (jc < CAP){ off = sbuf[wave][jc]; al = ebuf[wave][jc]; }
      else {
        int s = csr[beg+jc];
        off = s*64;
        float4 sv = *(const float4*)&s1src[s*4];
        al.x = __expf(lrelu(sv.x+sd.x)); al.y = __expf(lrelu(sv.y+sd.y));
        al.z = __expf(lrelu(sv.z+sd.z)); al.w = __expf(lrelu(sv.w+sd.w));
      }
      if (!v){ al.x=0.f; al.y=0.f; al.z=0.f; al.w=0.f; }
      uint2 u = *((const uint2*)(z8 + off) + li);
      agg8(u, al, c00, c01, c10, c11);
    }
  }
  float acc[2][4] = {{c00.x, c00.y, c01.x, c01.y},
                     {c10.x, c10.y, c11.x, c11.y}};
#pragma unroll
  for (int k = 0; k < 2; k++)
#pragma unroll
    for (int hh = 0; hh < 4; hh++) acc[k][hh] += __shfl_xor(acc[k][hh], 32, 64);
  const float* vv = &v2s[eh*256];
  float p = 0.f;
#pragma unroll
  for (int hh = 0; hh < 4; hh++){
    float e0 = acc[0][hh]*inv[hh]; e0 = e0 > 0.f ? e0 : expm1f(e0);
    float e1 = acc[1][hh]*inv[hh]; e1 = e1 > 0.f ? e1 : expm1f(e1);
    p += e0 * vv[hh*64 + 2*li] + e1 * vv[hh*64 + 2*li + 1];
    if ((hh >> 1) == eh)
      hneib[(size_t)dst*128 + hh*32 + li] = (uint_t)f2b(e0) | ((uint_t)f2b(e1) << 16);
  }
#pragma unroll
  for (int o = 1; o < 32; o <<= 1) p += __shfl_xor(p, o, 64);
  if (lane == 0)  s2s[dst] = p;
  if (lane == 32) s2d[dst] = p;
}

// ---------------- layer2 alpha-weights: XCD-local wsrc8 accumulation
__global__ __launch_bounds__(256) void k_aw2(
    const float* __restrict__ s2s, const float* __restrict__ s2d,
    const int* __restrict__ rowptr, const int* __restrict__ csr,
    float* __restrict__ wsrc8, int N)
{
  __shared__ int   sbuf[4][CAP];
  __shared__ float ebuf[4][CAP];
  const unsigned xcd = xcc_id();
  float* ws = wsrc8 + (size_t)xcd * N;
  const int wave = threadIdx.x >> 6, lane = threadIdx.x & 63;
  const int dst = blockIdx.x*4 + wave;
  if (dst >= N) return;
  const int beg = rowptr[dst], deg = rowptr[dst+1] - beg;
  const float sd = s2d[dst];
  float ts = 0.f;
  for (int j = lane; j < deg; j += 64){
    int s = csr[beg+j];
    float a = __expf(lrelu(s2s[s] + sd));
    if (j < CAP){ sbuf[wave][j] = s; ebuf[wave][j] = a; }
    ts += a;
  }
  const float inv = 1.f/wred_sum(ts);
  for (int j = lane; j < deg; j += 64){
    int s; float a;
    if (j < CAP){ s = sbuf[wave][j]; a = ebuf[wave][j]; }
    else { s = csr[beg+j]; a = __expf(lrelu(s2s[s] + sd)); }
    __hip_atomic_fetch_add(&ws[s], a * inv, __ATOMIC_RELAXED,
                           __HIP_MEMORY_SCOPE_WORKGROUP);
  }
}

// ---------------- weighted hnei sum (coalesced; wsrc = Σx wsrc8[x])
__global__ __launch_bounds__(256) void k_hsum(const uint_t* __restrict__ hneib,
    const float* __restrict__ wsrc8, float* __restrict__ acc256, int N)
{
  __shared__ float pr[512];
  const int t = threadIdx.x;
  const int h2 = t >> 7, p = t & 127;
  float a0 = 0.f, a1 = 0.f;
  const int step = gridDim.x * 2;
  for (int n = blockIdx.x*2 + h2; n < N; n += step){
    float wn = 0.f;
#pragma unroll
    for (int x = 0; x < 8; x++) wn += wsrc8[(size_t)x*N + n];
    uint_t u = hneib[(size_t)n*128 + p];
    a0 += wn * b2f_lo(u);
    a1 += wn * b2f_hi(u);
  }
  pr[h2*256 + 2*p]     = a0;
  pr[h2*256 + 2*p + 1] = a1;
  __syncthreads();
  float v = pr[t] + pr[256 + t];
  int pp = t >> 1;
  int d = (pp >> 5)*64 + 2*(pp & 31) + (t & 1);
  atomicAdd(&acc256[d], v);
}

// ---------------- finalize
__global__ __launch_bounds__(256) void k_finalize(const float* __restrict__ acc256,
    const float* __restrict__ accFrac, const float* __restrict__ W2,
    const float* __restrict__ frw, const float* __restrict__ frf,
    const float* __restrict__ fc2, float* __restrict__ out, float invN)
{
  __shared__ float mh[256], nei[64], g[384], mm[192], hfrac[64];
  int t = threadIdx.x;
  mh[t] = acc256[t] * invN;
  for (int i = t; i < 384; i += 256) g[i] = accFrac[i] * invN;
  __syncthreads();
  if (t < 64){
    float s = 0.f;
    for (int k = 0; k < 256; k++) s += W2[t*256 + k] * mh[k];
    nei[t] = s;
  }
  for (int i = t; i < 192; i += 256){
    int s = i >> 6, d = i & 63;
    const float* w = frw + (size_t)(s*64 + d)*128;
    const float* gs = g + s*128;
    float sum = 0.f;
    for (int k = 0; k < 128; k++) sum += gs[k]*w[k];
    mm[i] = sum;
  }
  __syncthreads();
  if (t < 64){
    float s = 0.f;
    for (int k = 0; k < 192; k++) s += mm[k]*frf[t*192 + k];
    hfrac[t] = s;
  }
  __syncthreads();
  if (t < 64){
    float o = 0.f;
    for (int k = 0; k < 64; k++)
      o += fc2[t*128 + k]*nei[k] + fc2[t*128 + 64 + k]*hfrac[k];
    out[t] = o;
  }
}

extern "C" void kernel_launch(void* const* d_in, const int* in_sizes, int n_in,
                              void* d_out, int out_size, void* d_ws, size_t ws_size,
                              hipStream_t stream)
{
  const float* h    = (const float*)d_in[0];
  const int*   srcI = (const int*)  d_in[1];
  const int*   dstI = (const int*)  d_in[2];
  const int*   fcm  = (const int*)  d_in[3];
  const float* l1fc = (const float*)d_in[4];
  const float* l1at = (const float*)d_in[5];
  const float* l2fc = (const float*)d_in[6];
  const float* l2at = (const float*)d_in[7];
  const float* frw  = (const float*)d_in[8];
  const float* frf  = (const float*)d_in[9];
  const float* fc2  = (const float*)d_in[10];
  float* out = (float*)d_out;
  (void)n_in; (void)out_size; (void)ws_size;

  const int N = in_sizes[0] / 128;
  const int E = in_sizes[1];
  const int B = (N + 256) / 256;     // ceil((N+1)/256) so rowptr[N] is covered
  const int PAD = B * 256;

  char* w = (char*)d_ws;
  size_t off = 0;
  auto alloc = [&](size_t bytes) -> char* {
    char* p = w + off; off = (off + bytes + 255) & ~(size_t)255; return p;
  };
  uint_t* z8    = (uint_t*)alloc((size_t)N*64*4);    // 25.6 MB fp8 z
  uint_t* hneib = (uint_t*)alloc((size_t)N*128*4);   // 51.2 MB packed bf16 hnei
  int*    rk    = (int*)hneib;                       // rank array aliases hneib
                                                     // (rk dead before gat1 writes hneib)
  float* s1s  = (float*)alloc((size_t)N*4*4);
  float* s1d  = (float*)alloc((size_t)N*4*4);
  float* s2s  = (float*)alloc((size_t)N*4);
  float* s2d  = (float*)alloc((size_t)N*4);
  // ---- zeroed region (one memset): deg8, cnt, wsrc8, acc256, accFrac
  int*   deg8    = (int*)  alloc((size_t)8*PAD*4);   // XCD-local histograms
  int*   cnt     = (int*)  alloc((size_t)N*3*4);     // fcm occurrence histogram
  float* wsrc8   = (float*)alloc((size_t)8*N*4);     // XCD-local alpha sums
  float* acc256  = (float*)alloc(256*4);
  float* accFrac = (float*)alloc(384*4);
  const size_t zbytes = (size_t)((char*)accFrac + 384*4 - (char*)deg8);
  // ---- rest
  int*   rowptr = (int*)alloc((size_t)PAD*4);
  int*   base8  = (int*)alloc((size_t)8*PAD*4);      // per-XCD sub-range starts
  int*   part   = (int*)alloc(512*4);
  int*   csr    = (int*)alloc((size_t)E*4);
  ushort_t* w1bp = (ushort_t*)alloc(34816*2);   // 16 z-tiles (permuted) + score tile
  float* v2     = (float*)alloc(512*4);

  hipMemsetAsync(deg8, 0, zbytes, stream);

  hipLaunchKernelGGL(k_prep,  dim3(130 + 512), dim3(256), 0, stream,
                     l1fc, l2fc, l1at, l2at, dstI, E, fcm, 3*N, cnt, w1bp, v2,
                     deg8, rk, PAD);
  hipLaunchKernelGGL(k_scan1, dim3(B),   dim3(256), 0, stream, deg8, part, PAD);
  hipLaunchKernelGGL(k_scan2, dim3(1),   dim3(512), 0, stream, part, B);
  hipLaunchKernelGGL(k_scan3, dim3(B),   dim3(256), 0, stream, deg8, part,
                     rowptr, base8, PAD);

  const int Gg = (N + 127) / 128;
  const int Gs = (E + 511) / 512;
  const int Gf = 512;
  const int G  = Gg + Gs + Gf;
  int step = (int)(G * 0.618) | 1;
  auto gcd = [](int a, int b){ while (b){ int t = a % b; a = b; b = t; } return a; };
  while (gcd(step, G) != 1) step += 2;

  hipLaunchKernelGGL(k_mega,  dim3(G), dim3(512), 0, stream,
                     h, w1bp, z8, s1s, s1d, N,
                     srcI, dstI, rk, base8, PAD, csr, E, Gg, Gs, G, step,
                     cnt, accFrac);
  hipLaunchKernelGGL(k_gat1,  dim3((N+3)/4), dim3(256), 0, stream,
                     z8, s1s, s1d, rowptr, csr, v2, hneib, s2s, s2d, N);
  hipLaunchKernelGGL(k_aw2,   dim3((N+3)/4), dim3(256), 0, stream,
                     s2s, s2d, rowptr, csr, wsrc8, N);
  hipLaunchKernelGGL(k_hsum,  dim3(608),     dim3(256), 0, stream,
                     hneib, wsrc8, acc256, N);
  hipLaunchKernelGGL(k_finalize, dim3(1),    dim3(256), 0, stream,
                     acc256, accFrac, l2fc, frw, frf, fc2, out, 1.0f/(float)N);
}